// Round 14
// baseline (48.850 us; speedup 1.0000x reference)
//
#include <hip/hip_runtime.h>
#include <hip/hip_bf16.h>
#include <math.h>

typedef __attribute__((ext_vector_type(8))) short short8;
typedef __attribute__((ext_vector_type(4))) short short4v;
typedef __attribute__((ext_vector_type(4))) float f32x4;
typedef __attribute__((ext_vector_type(2))) _Float16 h2;
typedef __attribute__((ext_vector_type(4))) _Float16 h4;
typedef __attribute__((ext_vector_type(8))) _Float16 h8;

__device__ __forceinline__ short f2bf(float f) {
    __hip_bfloat16 h = __float2bfloat16(f);   // RNE; pairs fuse to v_cvt_pk_bf16_f32
    return __builtin_bit_cast(short, h);
}

// ============================================================================
// Kernel A0 (unchanged): weight transpose + bf16 into d_ws.
// wT layout (shorts): W1T [128n][256k] @0 | W2T [64n][128k] @32768 |
//                     WcatT [192o][64k] @40960  (Wcat = [E1a|E1b|S1a|S1b])
// ============================================================================
__global__ __launch_bounds__(256)
void kernelA0(const float* __restrict__ W1, const float* __restrict__ W2,
              const float* __restrict__ E1, const float* __restrict__ S1,
              short* __restrict__ wT)
{
    const int tid = blockIdx.x * 256 + threadIdx.x;   // 32768
    {   // W1 [256k][128n] -> W1T[n][k]
        const int k = tid >> 7, n = tid & 127;
        wT[n * 256 + k] = f2bf(W1[tid]);
    }
    if (tid < 8192) {   // W2 [128k][64n] -> W2T[n][k]
        const int k = tid >> 6, n = tid & 63;
        wT[32768 + n * 128 + k] = f2bf(W2[tid]);
    }
    if (tid < 8192) {   // E1 [128][64] -> WcatT cols 0..127
        const int rr = tid >> 6, c = tid & 63;
        const int o = (rr < 64) ? c : (64 + c);
        const int k = (rr < 64) ? rr : (rr - 64);
        wT[40960 + o * 64 + k] = f2bf(E1[tid]);
    }
    if (tid < 4096) {   // S1 [128][32] -> WcatT cols 128..191
        const int rr = tid >> 5, c = tid & 31;
        const int o = (rr < 64) ? (128 + c) : (160 + c);
        const int k = (rr < 64) ? rr : (rr - 64);
        wT[40960 + o * 64 + k] = f2bf(S1[tid]);
    }
}

// ============================================================================
// Kernel F (round 14 = round 13 + __launch_bounds__(1024, 1)):
// r13 post-mortem: bare launch_bounds(1024) + DYNAMIC LDS -> compiler can't
// see 68.6KB forces 1 block/CU, targeted 2 blocks/CU, capped VGPR at 64 ->
// ~55MB/dispatch spill traffic (WRITE 64MB vs 12.6 real). arg=1 removes the
// cap; block size itself bounds V <= 128 (16 waves x V <= 2048/CU).
// Fused pipeline, 1024 thr/block, grid 256; 16B-aligned LDS strides (true
// b128 reads), deferred E-epilogue, bE2/E3 in registers, h8 S-pass.
// LDS aliasing: [0,33792) Xs -> after ph2: ei/ej/si/sj (f16);
//               [33792,..) h1B -> after ph3: nfB; [51200,..) Hs (f32).
// MFMA mapping HW-validated rounds 4-11.
// ============================================================================
constexpr int XS_S  = 264;  // shorts/row (528B = 33*16; 132dw %32=4)
constexpr int H1B_S = 136;  // shorts (272B = 17*16; 68dw %32=4)
constexpr int HS_S  = 68;   // floats (272B; %32=4)
constexpr int NNF_S = 72;   // shorts (144B = 9*16; 36dw %32=4)
constexpr int EJW   = 72;   // halfs/row ei/ej (144B = 9*16; 36dw %32=4)
constexpr int SJW   = 40;   // halfs/row si/sj (80B = 5*16; 20dw %32=20)

constexpr int OFF_XS  = 0;          // 33792 B
constexpr int OFF_EIH = 0;          // 9216 B  (64*72*2)
constexpr int OFF_EJH = 9216;       // 9216 B
constexpr int OFF_SIH = 18432;      // 5120 B  (64*40*2)
constexpr int OFF_SJH = 23552;      // 5120 B -> 28672 <= 33792
constexpr int OFF_H1B = 33792;      // 17408 B ; nfB alias
constexpr int OFF_HS  = 51200;      // 17408 B
constexpr int LDS_BYTES = 68608;

__global__ __launch_bounds__(1024, 1)
void kernelF(const float* __restrict__ x,
             const float* __restrict__ b1, const float* __restrict__ b2,
             const float* __restrict__ gamma, const float* __restrict__ beta,
             const short* __restrict__ wT,
             const float* __restrict__ bE1, const float* __restrict__ E2,
             const float* __restrict__ bE2, const float* __restrict__ E3,
             const float* __restrict__ bE3, const float* __restrict__ bS1,
             const float* __restrict__ S2, const float* __restrict__ bS2,
             float* __restrict__ out_nf, float* __restrict__ out_adj,
             float* __restrict__ out_str)
{
    extern __shared__ char lds[];
    short*    XsS  = (short*)(lds + OFF_XS);
    short*    h1BS = (short*)(lds + OFF_H1B);
    float*    HsS  = (float*)(lds + OFF_HS);
    short*    nfBS = (short*)(lds + OFF_H1B);    // alias (h1B dead after ph3)
    _Float16* eihS = (_Float16*)(lds + OFF_EIH); // alias (Xs dead after ph2)
    _Float16* ejhS = (_Float16*)(lds + OFF_EJH);
    _Float16* sihS = (_Float16*)(lds + OFF_SIH);
    _Float16* sjhS = (_Float16*)(lds + OFF_SJH);

    const int t = threadIdx.x, b = blockIdx.x;
    const int w = t >> 6, l = t & 63, g = l >> 4, r = l & 15;
    const short* W1T = wT;
    const short* W2T = wT + 32768;
    const short* WcT = wT + 40960;

    // ---- edge-stage constants in registers (global, L2-hot) ----
    h8 aE00, aE10, aE01, aE11;
#pragma unroll
    for (int e = 0; e < 8; ++e) {
        aE00[e] = (_Float16)E2[(size_t)(8 * g + e) * 32 + r];
        aE10[e] = (_Float16)E2[(size_t)(8 * g + e + 32) * 32 + r];
        aE01[e] = (_Float16)E2[(size_t)(8 * g + e) * 32 + r + 16];
        aE11[e] = (_Float16)E2[(size_t)(8 * g + e + 32) * 32 + r + 16];
    }
    const f32x4 bE2lo = *(const f32x4*)(bE2 + 4 * g);
    const f32x4 bE2hi = *(const f32x4*)(bE2 + 16 + 4 * g);
    const f32x4 e3lo  = *(const f32x4*)(E3 + 4 * g);
    const f32x4 e3hi  = *(const f32x4*)(E3 + 16 + 4 * g);
    const float bE3v = bE3[0], bS2v = bS2[0];
    const h8 z8 = {(_Float16)0.f, (_Float16)0.f, (_Float16)0.f, (_Float16)0.f,
                   (_Float16)0.f, (_Float16)0.f, (_Float16)0.f, (_Float16)0.f};

    // ---- stage X coalesced (64 rows, 16 threads/row, cvt bf16) ----
    {
        const int row = t >> 4, c0 = t & 15;
        const int srow = (row == 63) ? 127 : (int)((float)row * (127.0f / 63.0f));
        const float* xrow = x + ((size_t)b * 128 + srow) * 256;
#pragma unroll
        for (int i = 0; i < 4; ++i) {
            const int c4 = (c0 + 16 * i) * 4;
            const float4 v = *(const float4*)(xrow + c4);
            short4v s;
            s[0] = f2bf(v.x); s[1] = f2bf(v.y); s[2] = f2bf(v.z); s[3] = f2bf(v.w);
            *(short4v*)&XsS[row * XS_S + c4] = s;
        }
    }
    __syncthreads();

    // ---- ph2: h1[64][128] = relu(X@W1+b1); wave w: M-tile w>>2, N-tiles (w&3)*2+{0,1} ----
    {
        const int mt = w >> 2, nb = (w & 3) << 1;
        const int aRow = (16 * mt + r) * XS_S;
#pragma unroll
        for (int np = 0; np < 2; ++np) {
            const int n = ((nb + np) << 4) + r;
            f32x4 acca = {0.f, 0.f, 0.f, 0.f};
            f32x4 accb = {0.f, 0.f, 0.f, 0.f};
#pragma unroll
            for (int ks = 0; ks < 4; ++ks) {
                const short8 a0  = *(const short8*)&XsS[aRow + 32 * ks + 8 * g];
                const short8 a1  = *(const short8*)&XsS[aRow + 32 * (ks + 4) + 8 * g];
                const short8 bwa = *(const short8*)(W1T + (size_t)n * 256 + 32 * ks + 8 * g);
                const short8 bwb = *(const short8*)(W1T + (size_t)n * 256 + 32 * (ks + 4) + 8 * g);
                acca = __builtin_amdgcn_mfma_f32_16x16x32_bf16(a0, bwa, acca, 0, 0, 0);
                accb = __builtin_amdgcn_mfma_f32_16x16x32_bf16(a1, bwb, accb, 0, 0, 0);
            }
            const float b1v = b1[n];
#pragma unroll
            for (int q = 0; q < 4; ++q)
                h1BS[(16 * mt + 4 * g + q) * H1B_S + n] = f2bf(fmaxf(acca[q] + accb[q] + b1v, 0.f));
        }
    }
    __syncthreads();

    // ---- ph3: h[64][64] = h1@W2+b2; wave w: tile (w>>2, w&3) ----
    {
        const int mt = w >> 2;
        const int n = ((w & 3) << 4) + r;
        const int aRow = (16 * mt + r) * H1B_S;
        f32x4 acca = {0.f, 0.f, 0.f, 0.f};
        f32x4 accb = {0.f, 0.f, 0.f, 0.f};
#pragma unroll
        for (int ks2 = 0; ks2 < 2; ++ks2) {
            const short8 ha0 = *(const short8*)&h1BS[aRow + 32 * (2 * ks2) + 8 * g];
            const short8 ha1 = *(const short8*)&h1BS[aRow + 32 * (2 * ks2 + 1) + 8 * g];
            const short8 bw0 = *(const short8*)(W2T + (size_t)n * 128 + 32 * (2 * ks2) + 8 * g);
            const short8 bw1 = *(const short8*)(W2T + (size_t)n * 128 + 32 * (2 * ks2 + 1) + 8 * g);
            acca = __builtin_amdgcn_mfma_f32_16x16x32_bf16(ha0, bw0, acca, 0, 0, 0);
            accb = __builtin_amdgcn_mfma_f32_16x16x32_bf16(ha1, bw1, accb, 0, 0, 0);
        }
        const float b2v = b2[n];
#pragma unroll
        for (int q = 0; q < 4; ++q)
            HsS[(16 * mt + 4 * g + q) * HS_S + n] = acca[q] + accb[q] + b2v;
    }
    __syncthreads();

    // ---- ph4: LayerNorm; row = t>>4 (64 rows x 16 lanes exactly) ----
    {
        const int row = t >> 4, c4 = (t & 15) * 4;
        const float4 v = *(const float4*)&HsS[row * HS_S + c4];
        float s = v.x + v.y + v.z + v.w;
        s += __shfl_xor(s, 1); s += __shfl_xor(s, 2);
        s += __shfl_xor(s, 4); s += __shfl_xor(s, 8);
        const float mu = s * (1.0f / 64.0f);
        float vs = 0.f;
        { const float d0 = v.x-mu, d1 = v.y-mu, d2 = v.z-mu, d3 = v.w-mu;
          vs = fmaf(d0,d0, fmaf(d1,d1, fmaf(d2,d2, d3*d3))); }
        vs += __shfl_xor(vs, 1); vs += __shfl_xor(vs, 2);
        vs += __shfl_xor(vs, 4); vs += __shfl_xor(vs, 8);
        const float rstd = rsqrtf(vs * (1.0f / 64.0f) + 1e-5f);
        const float4 gv = *(const float4*)(gamma + c4);
        const float4 bv = *(const float4*)(beta  + c4);
        float4 o;
        o.x = fmaf((v.x - mu) * rstd, gv.x, bv.x);
        o.y = fmaf((v.y - mu) * rstd, gv.y, bv.y);
        o.z = fmaf((v.z - mu) * rstd, gv.z, bv.z);
        o.w = fmaf((v.w - mu) * rstd, gv.w, bv.w);
        *(float4*)(out_nf + (size_t)b * 4096 + (size_t)row * 64 + c4) = o;
        short4v ob;
        ob[0] = f2bf(o.x); ob[1] = f2bf(o.y); ob[2] = f2bf(o.z); ob[3] = f2bf(o.w);
        *(short4v*)&nfBS[row * NNF_S + c4] = ob;   // overwrites dead h1B region
    }
    __syncthreads();

    // ---- ph5: [ei|ej|si|sj] = nf@Wcat -> f16 LDS (Xs region), biases folded ----
    {
        const int mt = w >> 2;
        const short8 na0 = *(const short8*)&nfBS[(16 * mt + r) * NNF_S + 8 * g];
        const short8 na1 = *(const short8*)&nfBS[(16 * mt + r) * NNF_S + 32 + 8 * g];
#pragma unroll
        for (int k3 = 0; k3 < 3; ++k3) {
            const int ot = (w & 3) * 3 + k3;         // 0..11
            const int c = 16 * ot + r;
            const short8 bw0 = *(const short8*)(WcT + (size_t)c * 64 + 8 * g);
            const short8 bw1 = *(const short8*)(WcT + (size_t)c * 64 + 32 + 8 * g);
            f32x4 acc = {0.f, 0.f, 0.f, 0.f};
            acc = __builtin_amdgcn_mfma_f32_16x16x32_bf16(na0, bw0, acc, 0, 0, 0);
            acc = __builtin_amdgcn_mfma_f32_16x16x32_bf16(na1, bw1, acc, 0, 0, 0);
            if (ot < 4) {
                const float bv = bE1[c];
#pragma unroll
                for (int q = 0; q < 4; ++q)
                    eihS[(16 * mt + 4 * g + q) * EJW + c] = (_Float16)(acc[q] + bv);
            } else if (ot < 8) {
#pragma unroll
                for (int q = 0; q < 4; ++q)
                    ejhS[(16 * mt + 4 * g + q) * EJW + (c - 64)] = (_Float16)acc[q];
            } else if (ot < 10) {
                const float bv = bS1[c - 128];
#pragma unroll
                for (int q = 0; q < 4; ++q)
                    sihS[(16 * mt + 4 * g + q) * SJW + (c - 128)] = (_Float16)(acc[q] + bv);
            } else {
#pragma unroll
                for (int q = 0; q < 4; ++q)
                    sjhS[(16 * mt + 4 * g + q) * SJW + (c - 160)] = (_Float16)acc[q];
            }
        }
    }
    __syncthreads();

    // ---- E pass: wave w owns i-rows 4w..4w+3; DEFERRED epilogue ----
    {
        float peA[4][4];                 // [jt][ii] per-lane partials
#pragma unroll
        for (int jt = 0; jt < 4; ++jt) {
            const int j = (jt << 4) + r;
            const h8 ej0 = *(const h8*)&ejhS[j * EJW + 8 * g];
            const h8 ej1 = *(const h8*)&ejhS[j * EJW + 32 + 8 * g];

#pragma unroll
            for (int ii = 0; ii < 4; ++ii) {
                const int il = 4 * w + ii;
                const h8 ei0 = *(const h8*)&eihS[il * EJW + 8 * g];       // CSE'd across jt
                const h8 ei1 = *(const h8*)&eihS[il * EJW + 32 + 8 * g];

                const h8 b0 = __builtin_elementwise_max(ei0 + ej0, z8);
                const h8 b1 = __builtin_elementwise_max(ei1 + ej1, z8);

                f32x4 acc0 = {0.f, 0.f, 0.f, 0.f};
                f32x4 acc1 = {0.f, 0.f, 0.f, 0.f};
                acc0 = __builtin_amdgcn_mfma_f32_16x16x32_f16(aE00, b0, acc0, 0, 0, 0);
                acc0 = __builtin_amdgcn_mfma_f32_16x16x32_f16(aE10, b1, acc0, 0, 0, 0);
                acc1 = __builtin_amdgcn_mfma_f32_16x16x32_f16(aE01, b0, acc1, 0, 0, 0);
                acc1 = __builtin_amdgcn_mfma_f32_16x16x32_f16(aE11, b1, acc1, 0, 0, 0);

                float pe = 0.f;
#pragma unroll
                for (int q = 0; q < 4; ++q) {
                    pe = fmaf(fmaxf(acc0[q] + bE2lo[q], 0.f), e3lo[q], pe);
                    pe = fmaf(fmaxf(acc1[q] + bE2hi[q], 0.f), e3hi[q], pe);
                }
                peA[jt][ii] = pe;
            }
        }

        // batched reduce + sigmoid + store (16 independent shuffle chains)
#pragma unroll
        for (int jt = 0; jt < 4; ++jt) {
#pragma unroll
            for (int ii = 0; ii < 4; ++ii) {
                float pe = peA[jt][ii];
                pe += __shfl_xor(pe, 16);
                pe += __shfl_xor(pe, 32);
                if (l < 16) {
                    const int ig = 4 * w + ii;
                    const int j  = (jt << 4) + r;
                    const float z = pe + bE3v;
                    const float p = 1.0f / (1.0f + __expf(-z));
                    const float av = (j == ig || !(p > 0.3f)) ? 0.f : p;
                    out_adj[(size_t)b * 4096 + (size_t)ig * 64 + j] = av;
                }
            }
        }
    }

    // ---- S pass: thread t: j = t&63, i-rows (t>>6)*4..; h8 + fdot2 ----
    {
        h8 s2v[4];
#pragma unroll
        for (int c = 0; c < 4; ++c) {
            h8 p;
#pragma unroll
            for (int e = 0; e < 8; ++e) p[e] = (_Float16)S2[8 * c + e];
            s2v[c] = p;
        }
        const int j = t & 63;
        const int ib = (t >> 6) * 4;
        h8 sj8[4];
#pragma unroll
        for (int c = 0; c < 4; ++c)
            sj8[c] = *(const h8*)&sjhS[j * SJW + 8 * c];
#pragma unroll
        for (int ii = 0; ii < 4; ++ii) {
            const int ig = ib + ii;
            float sacc = 0.f;
#pragma unroll
            for (int c = 0; c < 4; ++c) {
                const h8 si8 = *(const h8*)&sihS[ig * SJW + 8 * c];   // broadcast
                const h8 hs = __builtin_elementwise_max(si8 + sj8[c], z8);
                const h2 p0 = __builtin_shufflevector(hs, hs, 0, 1);
                const h2 p1 = __builtin_shufflevector(hs, hs, 2, 3);
                const h2 p2 = __builtin_shufflevector(hs, hs, 4, 5);
                const h2 p3 = __builtin_shufflevector(hs, hs, 6, 7);
                const h2 q0 = __builtin_shufflevector(s2v[c], s2v[c], 0, 1);
                const h2 q1 = __builtin_shufflevector(s2v[c], s2v[c], 2, 3);
                const h2 q2 = __builtin_shufflevector(s2v[c], s2v[c], 4, 5);
                const h2 q3 = __builtin_shufflevector(s2v[c], s2v[c], 6, 7);
                sacc = __builtin_amdgcn_fdot2(p0, q0, sacc, false);
                sacc = __builtin_amdgcn_fdot2(p1, q1, sacc, false);
                sacc = __builtin_amdgcn_fdot2(p2, q2, sacc, false);
                sacc = __builtin_amdgcn_fdot2(p3, q3, sacc, false);
            }
            const float xs = sacc + bS2v;
            const float e2x = __expf(2.0f * xs);
            const float sv = (j == ig) ? 0.f : (e2x - 1.0f) / (e2x + 1.0f);
            out_str[(size_t)b * 4096 + (size_t)ig * 64 + j] = sv;
        }
    }
}

extern "C" void kernel_launch(void* const* d_in, const int* in_sizes, int n_in,
                              void* d_out, int out_size, void* d_ws, size_t ws_size,
                              hipStream_t stream)
{
    const float* x     = (const float*)d_in[0];
    const float* W1    = (const float*)d_in[1];
    const float* b1    = (const float*)d_in[2];
    const float* W2    = (const float*)d_in[3];
    const float* b2    = (const float*)d_in[4];
    const float* gamma = (const float*)d_in[5];
    const float* beta  = (const float*)d_in[6];
    const float* E1    = (const float*)d_in[7];
    const float* bE1   = (const float*)d_in[8];
    const float* E2    = (const float*)d_in[9];
    const float* bE2   = (const float*)d_in[10];
    const float* E3    = (const float*)d_in[11];
    const float* bE3   = (const float*)d_in[12];
    const float* S1    = (const float*)d_in[13];
    const float* bS1   = (const float*)d_in[14];
    const float* S2    = (const float*)d_in[15];
    const float* bS2   = (const float*)d_in[16];

    float* out     = (float*)d_out;
    float* out_nf  = out;                // 256*64*64
    float* out_adj = out + 1048576;
    float* out_str = out + 2097152;

    short* wT = (short*)d_ws;            // 104 KB scratch, rewritten every call

    (void)hipFuncSetAttribute((const void*)kernelF,
        hipFuncAttributeMaxDynamicSharedMemorySize, LDS_BYTES);

    kernelA0<<<128, 256, 0, stream>>>(W1, W2, E1, S1, wT);

    kernelF<<<256, 1024, LDS_BYTES, stream>>>(
        x, b1, b2, gamma, beta, wT,
        bE1, E2, bE2, E3, bE3, bS1, S2, bS2,
        out_nf, out_adj, out_str);
}

// Round 15
// 47.933 us; speedup vs baseline: 1.0191x; 1.0191x over previous
//
#include <hip/hip_runtime.h>
#include <hip/hip_bf16.h>
#include <math.h>

typedef __attribute__((ext_vector_type(8))) short short8;
typedef __attribute__((ext_vector_type(4))) short short4v;
typedef __attribute__((ext_vector_type(4))) float f32x4;
typedef __attribute__((ext_vector_type(2))) _Float16 h2;
typedef __attribute__((ext_vector_type(4))) _Float16 h4;
typedef __attribute__((ext_vector_type(8))) _Float16 h8;

__device__ __forceinline__ short f2bf(float f) {
    __hip_bfloat16 h = __float2bfloat16(f);   // RNE; pairs fuse to v_cvt_pk_bf16_f32
    return __builtin_bit_cast(short, h);
}

// ============================================================================
// Kernel A0 (unchanged): weight transpose + bf16 into d_ws.
// wT layout (shorts): W1T [128n][256k] @0 | W2T [64n][128k] @32768 |
//                     WcatT [192o][64k] @40960  (Wcat = [E1a|E1b|S1a|S1b])
// ============================================================================
__global__ __launch_bounds__(256)
void kernelA0(const float* __restrict__ W1, const float* __restrict__ W2,
              const float* __restrict__ E1, const float* __restrict__ S1,
              short* __restrict__ wT)
{
    const int tid = blockIdx.x * 256 + threadIdx.x;   // 32768
    {   // W1 [256k][128n] -> W1T[n][k]
        const int k = tid >> 7, n = tid & 127;
        wT[n * 256 + k] = f2bf(W1[tid]);
    }
    if (tid < 8192) {   // W2 [128k][64n] -> W2T[n][k]
        const int k = tid >> 6, n = tid & 63;
        wT[32768 + n * 128 + k] = f2bf(W2[tid]);
    }
    if (tid < 8192) {   // E1 [128][64] -> WcatT cols 0..127
        const int rr = tid >> 6, c = tid & 63;
        const int o = (rr < 64) ? c : (64 + c);
        const int k = (rr < 64) ? rr : (rr - 64);
        wT[40960 + o * 64 + k] = f2bf(E1[tid]);
    }
    if (tid < 4096) {   // S1 [128][32] -> WcatT cols 128..191
        const int rr = tid >> 5, c = tid & 31;
        const int o = (rr < 64) ? (128 + c) : (160 + c);
        const int k = (rr < 64) ? rr : (rr - 64);
        wT[40960 + o * 64 + k] = f2bf(S1[tid]);
    }
}

// ============================================================================
// Kernel F (round 15 = round 13/14 body + amdgpu_waves_per_eu(4,4)):
// VGPR-cap series: (256,1)->148 free, (256,2)->128, (256,4)->64, (1024,*)->64.
// For 1024-thr blocks the backend derives waves/EU from flat workgroup size
// and ignores launch_bounds' 2nd arg -> stuck at 64 VGPR, ~55MB/dispatch
// spill (r13/r14: WRITE 64MB vs 12.6 real). amdgpu_waves_per_eu(4,4) pins
// the allocator's occupancy assumption to our ACTUAL config (1 blk/CU x 16
// waves = 4/EU) -> budget 128 VGPR; body needs ~100-110 live.
// Fused pipeline, 1024 thr/block, grid 256; 16B-aligned LDS strides (true
// b128 reads), deferred E-epilogue, bE2/E3 in registers, h8 S-pass.
// LDS aliasing: [0,33792) Xs -> after ph2: ei/ej/si/sj (f16);
//               [33792,..) h1B -> after ph3: nfB; [51200,..) Hs (f32).
// MFMA mapping HW-validated rounds 4-11.
// ============================================================================
constexpr int XS_S  = 264;  // shorts/row (528B = 33*16; 132dw %32=4)
constexpr int H1B_S = 136;  // shorts (272B = 17*16; 68dw %32=4)
constexpr int HS_S  = 68;   // floats (272B; %32=4)
constexpr int NNF_S = 72;   // shorts (144B = 9*16; 36dw %32=4)
constexpr int EJW   = 72;   // halfs/row ei/ej (144B = 9*16; 36dw %32=4)
constexpr int SJW   = 40;   // halfs/row si/sj (80B = 5*16; 20dw %32=20)

constexpr int OFF_XS  = 0;          // 33792 B
constexpr int OFF_EIH = 0;          // 9216 B  (64*72*2)
constexpr int OFF_EJH = 9216;       // 9216 B
constexpr int OFF_SIH = 18432;      // 5120 B  (64*40*2)
constexpr int OFF_SJH = 23552;      // 5120 B -> 28672 <= 33792
constexpr int OFF_H1B = 33792;      // 17408 B ; nfB alias
constexpr int OFF_HS  = 51200;      // 17408 B
constexpr int LDS_BYTES = 68608;

__global__ __launch_bounds__(1024)
__attribute__((amdgpu_waves_per_eu(4, 4)))
void kernelF(const float* __restrict__ x,
             const float* __restrict__ b1, const float* __restrict__ b2,
             const float* __restrict__ gamma, const float* __restrict__ beta,
             const short* __restrict__ wT,
             const float* __restrict__ bE1, const float* __restrict__ E2,
             const float* __restrict__ bE2, const float* __restrict__ E3,
             const float* __restrict__ bE3, const float* __restrict__ bS1,
             const float* __restrict__ S2, const float* __restrict__ bS2,
             float* __restrict__ out_nf, float* __restrict__ out_adj,
             float* __restrict__ out_str)
{
    extern __shared__ char lds[];
    short*    XsS  = (short*)(lds + OFF_XS);
    short*    h1BS = (short*)(lds + OFF_H1B);
    float*    HsS  = (float*)(lds + OFF_HS);
    short*    nfBS = (short*)(lds + OFF_H1B);    // alias (h1B dead after ph3)
    _Float16* eihS = (_Float16*)(lds + OFF_EIH); // alias (Xs dead after ph2)
    _Float16* ejhS = (_Float16*)(lds + OFF_EJH);
    _Float16* sihS = (_Float16*)(lds + OFF_SIH);
    _Float16* sjhS = (_Float16*)(lds + OFF_SJH);

    const int t = threadIdx.x, b = blockIdx.x;
    const int w = t >> 6, l = t & 63, g = l >> 4, r = l & 15;
    const short* W1T = wT;
    const short* W2T = wT + 32768;
    const short* WcT = wT + 40960;

    // ---- edge-stage constants in registers (global, L2-hot) ----
    h8 aE00, aE10, aE01, aE11;
#pragma unroll
    for (int e = 0; e < 8; ++e) {
        aE00[e] = (_Float16)E2[(size_t)(8 * g + e) * 32 + r];
        aE10[e] = (_Float16)E2[(size_t)(8 * g + e + 32) * 32 + r];
        aE01[e] = (_Float16)E2[(size_t)(8 * g + e) * 32 + r + 16];
        aE11[e] = (_Float16)E2[(size_t)(8 * g + e + 32) * 32 + r + 16];
    }
    const f32x4 bE2lo = *(const f32x4*)(bE2 + 4 * g);
    const f32x4 bE2hi = *(const f32x4*)(bE2 + 16 + 4 * g);
    const f32x4 e3lo  = *(const f32x4*)(E3 + 4 * g);
    const f32x4 e3hi  = *(const f32x4*)(E3 + 16 + 4 * g);
    const float bE3v = bE3[0], bS2v = bS2[0];
    const h8 z8 = {(_Float16)0.f, (_Float16)0.f, (_Float16)0.f, (_Float16)0.f,
                   (_Float16)0.f, (_Float16)0.f, (_Float16)0.f, (_Float16)0.f};

    // ---- stage X coalesced (64 rows, 16 threads/row, cvt bf16) ----
    {
        const int row = t >> 4, c0 = t & 15;
        const int srow = (row == 63) ? 127 : (int)((float)row * (127.0f / 63.0f));
        const float* xrow = x + ((size_t)b * 128 + srow) * 256;
#pragma unroll
        for (int i = 0; i < 4; ++i) {
            const int c4 = (c0 + 16 * i) * 4;
            const float4 v = *(const float4*)(xrow + c4);
            short4v s;
            s[0] = f2bf(v.x); s[1] = f2bf(v.y); s[2] = f2bf(v.z); s[3] = f2bf(v.w);
            *(short4v*)&XsS[row * XS_S + c4] = s;
        }
    }
    __syncthreads();

    // ---- ph2: h1[64][128] = relu(X@W1+b1); wave w: M-tile w>>2, N-tiles (w&3)*2+{0,1} ----
    {
        const int mt = w >> 2, nb = (w & 3) << 1;
        const int aRow = (16 * mt + r) * XS_S;
#pragma unroll
        for (int np = 0; np < 2; ++np) {
            const int n = ((nb + np) << 4) + r;
            f32x4 acca = {0.f, 0.f, 0.f, 0.f};
            f32x4 accb = {0.f, 0.f, 0.f, 0.f};
#pragma unroll
            for (int ks = 0; ks < 4; ++ks) {
                const short8 a0  = *(const short8*)&XsS[aRow + 32 * ks + 8 * g];
                const short8 a1  = *(const short8*)&XsS[aRow + 32 * (ks + 4) + 8 * g];
                const short8 bwa = *(const short8*)(W1T + (size_t)n * 256 + 32 * ks + 8 * g);
                const short8 bwb = *(const short8*)(W1T + (size_t)n * 256 + 32 * (ks + 4) + 8 * g);
                acca = __builtin_amdgcn_mfma_f32_16x16x32_bf16(a0, bwa, acca, 0, 0, 0);
                accb = __builtin_amdgcn_mfma_f32_16x16x32_bf16(a1, bwb, accb, 0, 0, 0);
            }
            const float b1v = b1[n];
#pragma unroll
            for (int q = 0; q < 4; ++q)
                h1BS[(16 * mt + 4 * g + q) * H1B_S + n] = f2bf(fmaxf(acca[q] + accb[q] + b1v, 0.f));
        }
    }
    __syncthreads();

    // ---- ph3: h[64][64] = h1@W2+b2; wave w: tile (w>>2, w&3) ----
    {
        const int mt = w >> 2;
        const int n = ((w & 3) << 4) + r;
        const int aRow = (16 * mt + r) * H1B_S;
        f32x4 acca = {0.f, 0.f, 0.f, 0.f};
        f32x4 accb = {0.f, 0.f, 0.f, 0.f};
#pragma unroll
        for (int ks2 = 0; ks2 < 2; ++ks2) {
            const short8 ha0 = *(const short8*)&h1BS[aRow + 32 * (2 * ks2) + 8 * g];
            const short8 ha1 = *(const short8*)&h1BS[aRow + 32 * (2 * ks2 + 1) + 8 * g];
            const short8 bw0 = *(const short8*)(W2T + (size_t)n * 128 + 32 * (2 * ks2) + 8 * g);
            const short8 bw1 = *(const short8*)(W2T + (size_t)n * 128 + 32 * (2 * ks2 + 1) + 8 * g);
            acca = __builtin_amdgcn_mfma_f32_16x16x32_bf16(ha0, bw0, acca, 0, 0, 0);
            accb = __builtin_amdgcn_mfma_f32_16x16x32_bf16(ha1, bw1, accb, 0, 0, 0);
        }
        const float b2v = b2[n];
#pragma unroll
        for (int q = 0; q < 4; ++q)
            HsS[(16 * mt + 4 * g + q) * HS_S + n] = acca[q] + accb[q] + b2v;
    }
    __syncthreads();

    // ---- ph4: LayerNorm; row = t>>4 (64 rows x 16 lanes exactly) ----
    {
        const int row = t >> 4, c4 = (t & 15) * 4;
        const float4 v = *(const float4*)&HsS[row * HS_S + c4];
        float s = v.x + v.y + v.z + v.w;
        s += __shfl_xor(s, 1); s += __shfl_xor(s, 2);
        s += __shfl_xor(s, 4); s += __shfl_xor(s, 8);
        const float mu = s * (1.0f / 64.0f);
        float vs = 0.f;
        { const float d0 = v.x-mu, d1 = v.y-mu, d2 = v.z-mu, d3 = v.w-mu;
          vs = fmaf(d0,d0, fmaf(d1,d1, fmaf(d2,d2, d3*d3))); }
        vs += __shfl_xor(vs, 1); vs += __shfl_xor(vs, 2);
        vs += __shfl_xor(vs, 4); vs += __shfl_xor(vs, 8);
        const float rstd = rsqrtf(vs * (1.0f / 64.0f) + 1e-5f);
        const float4 gv = *(const float4*)(gamma + c4);
        const float4 bv = *(const float4*)(beta  + c4);
        float4 o;
        o.x = fmaf((v.x - mu) * rstd, gv.x, bv.x);
        o.y = fmaf((v.y - mu) * rstd, gv.y, bv.y);
        o.z = fmaf((v.z - mu) * rstd, gv.z, bv.z);
        o.w = fmaf((v.w - mu) * rstd, gv.w, bv.w);
        *(float4*)(out_nf + (size_t)b * 4096 + (size_t)row * 64 + c4) = o;
        short4v ob;
        ob[0] = f2bf(o.x); ob[1] = f2bf(o.y); ob[2] = f2bf(o.z); ob[3] = f2bf(o.w);
        *(short4v*)&nfBS[row * NNF_S + c4] = ob;   // overwrites dead h1B region
    }
    __syncthreads();

    // ---- ph5: [ei|ej|si|sj] = nf@Wcat -> f16 LDS (Xs region), biases folded ----
    {
        const int mt = w >> 2;
        const short8 na0 = *(const short8*)&nfBS[(16 * mt + r) * NNF_S + 8 * g];
        const short8 na1 = *(const short8*)&nfBS[(16 * mt + r) * NNF_S + 32 + 8 * g];
#pragma unroll
        for (int k3 = 0; k3 < 3; ++k3) {
            const int ot = (w & 3) * 3 + k3;         // 0..11
            const int c = 16 * ot + r;
            const short8 bw0 = *(const short8*)(WcT + (size_t)c * 64 + 8 * g);
            const short8 bw1 = *(const short8*)(WcT + (size_t)c * 64 + 32 + 8 * g);
            f32x4 acc = {0.f, 0.f, 0.f, 0.f};
            acc = __builtin_amdgcn_mfma_f32_16x16x32_bf16(na0, bw0, acc, 0, 0, 0);
            acc = __builtin_amdgcn_mfma_f32_16x16x32_bf16(na1, bw1, acc, 0, 0, 0);
            if (ot < 4) {
                const float bv = bE1[c];
#pragma unroll
                for (int q = 0; q < 4; ++q)
                    eihS[(16 * mt + 4 * g + q) * EJW + c] = (_Float16)(acc[q] + bv);
            } else if (ot < 8) {
#pragma unroll
                for (int q = 0; q < 4; ++q)
                    ejhS[(16 * mt + 4 * g + q) * EJW + (c - 64)] = (_Float16)acc[q];
            } else if (ot < 10) {
                const float bv = bS1[c - 128];
#pragma unroll
                for (int q = 0; q < 4; ++q)
                    sihS[(16 * mt + 4 * g + q) * SJW + (c - 128)] = (_Float16)(acc[q] + bv);
            } else {
#pragma unroll
                for (int q = 0; q < 4; ++q)
                    sjhS[(16 * mt + 4 * g + q) * SJW + (c - 160)] = (_Float16)acc[q];
            }
        }
    }
    __syncthreads();

    // ---- E pass: wave w owns i-rows 4w..4w+3; DEFERRED epilogue ----
    {
        float peA[4][4];                 // [jt][ii] per-lane partials
#pragma unroll
        for (int jt = 0; jt < 4; ++jt) {
            const int j = (jt << 4) + r;
            const h8 ej0 = *(const h8*)&ejhS[j * EJW + 8 * g];
            const h8 ej1 = *(const h8*)&ejhS[j * EJW + 32 + 8 * g];

#pragma unroll
            for (int ii = 0; ii < 4; ++ii) {
                const int il = 4 * w + ii;
                const h8 ei0 = *(const h8*)&eihS[il * EJW + 8 * g];       // CSE'd across jt
                const h8 ei1 = *(const h8*)&eihS[il * EJW + 32 + 8 * g];

                const h8 b0 = __builtin_elementwise_max(ei0 + ej0, z8);
                const h8 b1 = __builtin_elementwise_max(ei1 + ej1, z8);

                f32x4 acc0 = {0.f, 0.f, 0.f, 0.f};
                f32x4 acc1 = {0.f, 0.f, 0.f, 0.f};
                acc0 = __builtin_amdgcn_mfma_f32_16x16x32_f16(aE00, b0, acc0, 0, 0, 0);
                acc0 = __builtin_amdgcn_mfma_f32_16x16x32_f16(aE10, b1, acc0, 0, 0, 0);
                acc1 = __builtin_amdgcn_mfma_f32_16x16x32_f16(aE01, b0, acc1, 0, 0, 0);
                acc1 = __builtin_amdgcn_mfma_f32_16x16x32_f16(aE11, b1, acc1, 0, 0, 0);

                float pe = 0.f;
#pragma unroll
                for (int q = 0; q < 4; ++q) {
                    pe = fmaf(fmaxf(acc0[q] + bE2lo[q], 0.f), e3lo[q], pe);
                    pe = fmaf(fmaxf(acc1[q] + bE2hi[q], 0.f), e3hi[q], pe);
                }
                peA[jt][ii] = pe;
            }
        }

        // batched reduce + sigmoid + store (16 independent shuffle chains)
#pragma unroll
        for (int jt = 0; jt < 4; ++jt) {
#pragma unroll
            for (int ii = 0; ii < 4; ++ii) {
                float pe = peA[jt][ii];
                pe += __shfl_xor(pe, 16);
                pe += __shfl_xor(pe, 32);
                if (l < 16) {
                    const int ig = 4 * w + ii;
                    const int j  = (jt << 4) + r;
                    const float z = pe + bE3v;
                    const float p = 1.0f / (1.0f + __expf(-z));
                    const float av = (j == ig || !(p > 0.3f)) ? 0.f : p;
                    out_adj[(size_t)b * 4096 + (size_t)ig * 64 + j] = av;
                }
            }
        }
    }

    // ---- S pass: thread t: j = t&63, i-rows (t>>6)*4..; h8 + fdot2 ----
    {
        h8 s2v[4];
#pragma unroll
        for (int c = 0; c < 4; ++c) {
            h8 p;
#pragma unroll
            for (int e = 0; e < 8; ++e) p[e] = (_Float16)S2[8 * c + e];
            s2v[c] = p;
        }
        const int j = t & 63;
        const int ib = (t >> 6) * 4;
        h8 sj8[4];
#pragma unroll
        for (int c = 0; c < 4; ++c)
            sj8[c] = *(const h8*)&sjhS[j * SJW + 8 * c];
#pragma unroll
        for (int ii = 0; ii < 4; ++ii) {
            const int ig = ib + ii;
            float sacc = 0.f;
#pragma unroll
            for (int c = 0; c < 4; ++c) {
                const h8 si8 = *(const h8*)&sihS[ig * SJW + 8 * c];   // broadcast
                const h8 hs = __builtin_elementwise_max(si8 + sj8[c], z8);
                const h2 p0 = __builtin_shufflevector(hs, hs, 0, 1);
                const h2 p1 = __builtin_shufflevector(hs, hs, 2, 3);
                const h2 p2 = __builtin_shufflevector(hs, hs, 4, 5);
                const h2 p3 = __builtin_shufflevector(hs, hs, 6, 7);
                const h2 q0 = __builtin_shufflevector(s2v[c], s2v[c], 0, 1);
                const h2 q1 = __builtin_shufflevector(s2v[c], s2v[c], 2, 3);
                const h2 q2 = __builtin_shufflevector(s2v[c], s2v[c], 4, 5);
                const h2 q3 = __builtin_shufflevector(s2v[c], s2v[c], 6, 7);
                sacc = __builtin_amdgcn_fdot2(p0, q0, sacc, false);
                sacc = __builtin_amdgcn_fdot2(p1, q1, sacc, false);
                sacc = __builtin_amdgcn_fdot2(p2, q2, sacc, false);
                sacc = __builtin_amdgcn_fdot2(p3, q3, sacc, false);
            }
            const float xs = sacc + bS2v;
            const float e2x = __expf(2.0f * xs);
            const float sv = (j == ig) ? 0.f : (e2x - 1.0f) / (e2x + 1.0f);
            out_str[(size_t)b * 4096 + (size_t)ig * 64 + j] = sv;
        }
    }
}

extern "C" void kernel_launch(void* const* d_in, const int* in_sizes, int n_in,
                              void* d_out, int out_size, void* d_ws, size_t ws_size,
                              hipStream_t stream)
{
    const float* x     = (const float*)d_in[0];
    const float* W1    = (const float*)d_in[1];
    const float* b1    = (const float*)d_in[2];
    const float* W2    = (const float*)d_in[3];
    const float* b2    = (const float*)d_in[4];
    const float* gamma = (const float*)d_in[5];
    const float* beta  = (const float*)d_in[6];
    const float* E1    = (const float*)d_in[7];
    const float* bE1   = (const float*)d_in[8];
    const float* E2    = (const float*)d_in[9];
    const float* bE2   = (const float*)d_in[10];
    const float* E3    = (const float*)d_in[11];
    const float* bE3   = (const float*)d_in[12];
    const float* S1    = (const float*)d_in[13];
    const float* bS1   = (const float*)d_in[14];
    const float* S2    = (const float*)d_in[15];
    const float* bS2   = (const float*)d_in[16];

    float* out     = (float*)d_out;
    float* out_nf  = out;                // 256*64*64
    float* out_adj = out + 1048576;
    float* out_str = out + 2097152;

    short* wT = (short*)d_ws;            // 104 KB scratch, rewritten every call

    (void)hipFuncSetAttribute((const void*)kernelF,
        hipFuncAttributeMaxDynamicSharedMemorySize, LDS_BYTES);

    kernelA0<<<128, 256, 0, stream>>>(W1, W2, E1, S1, wT);

    kernelF<<<256, 1024, LDS_BYTES, stream>>>(
        x, b1, b2, gamma, beta, wT,
        bE1, E2, bE2, E3, bE3, bS1, S2, bS2,
        out_nf, out_adj, out_str);
}

// Round 16
// 38.446 us; speedup vs baseline: 1.2706x; 1.2468x over previous
//
#include <hip/hip_runtime.h>
#include <hip/hip_bf16.h>
#include <math.h>

typedef __attribute__((ext_vector_type(8))) short short8;
typedef __attribute__((ext_vector_type(4))) short short4v;
typedef __attribute__((ext_vector_type(4))) float f32x4;
typedef __attribute__((ext_vector_type(2))) _Float16 h2;
typedef __attribute__((ext_vector_type(4))) _Float16 h4;
typedef __attribute__((ext_vector_type(8))) _Float16 h8;

__device__ __forceinline__ short f2bf(float f) {
    __hip_bfloat16 h = __float2bfloat16(f);   // RNE; pairs fuse to v_cvt_pk_bf16_f32
    return __builtin_bit_cast(short, h);
}

// ============================================================================
// Kernel A0 (unchanged): weight transpose + bf16 into d_ws.
// wT layout (shorts): W1T [128n][256k] @0 | W2T [64n][128k] @32768 |
//                     WcatT [192o][64k] @40960  (Wcat = [E1a|E1b|S1a|S1b])
// ============================================================================
__global__ __launch_bounds__(256)
void kernelA0(const float* __restrict__ W1, const float* __restrict__ W2,
              const float* __restrict__ E1, const float* __restrict__ S1,
              short* __restrict__ wT)
{
    const int tid = blockIdx.x * 256 + threadIdx.x;   // 32768
    {   // W1 [256k][128n] -> W1T[n][k]
        const int k = tid >> 7, n = tid & 127;
        wT[n * 256 + k] = f2bf(W1[tid]);
    }
    if (tid < 8192) {   // W2 [128k][64n] -> W2T[n][k]
        const int k = tid >> 6, n = tid & 63;
        wT[32768 + n * 128 + k] = f2bf(W2[tid]);
    }
    if (tid < 8192) {   // E1 [128][64] -> WcatT cols 0..127
        const int rr = tid >> 6, c = tid & 63;
        const int o = (rr < 64) ? c : (64 + c);
        const int k = (rr < 64) ? rr : (rr - 64);
        wT[40960 + o * 64 + k] = f2bf(E1[tid]);
    }
    if (tid < 4096) {   // S1 [128][32] -> WcatT cols 128..191
        const int rr = tid >> 5, c = tid & 31;
        const int o = (rr < 64) ? (128 + c) : (160 + c);
        const int k = (rr < 64) ? rr : (rr - 64);
        wT[40960 + o * 64 + k] = f2bf(S1[tid]);
    }
}

// ============================================================================
// Kernel F (round 16): SLIM body designed for the 64-VGPR budget.
// r12-r15 lesson: 1024-thr kernels are hard-capped at 64 arch VGPRs on this
// toolchain (launch_bounds 2nd arg + amdgpu_waves_per_eu both ineffective;
// SGPR responded to the attribute, VGPR did not). r13's body had ~110 live ->
// ~55MB/dispatch spill. This body keeps only register-neutral r12 wins:
// 16B-aligned strides (true ds_read_b128). Constants (bE2/E3/S2) live in LDS;
// inline E-epilogue (no peA[16]); no ei/sj register hoists.
// LDS aliasing: [0,33792) Xs -> after ph2: ei/ej/si/sj (f16);
//               [33792,..) h1B -> after ph3: nfB; [51200,..) Hs (f32).
// MFMA mapping HW-validated rounds 4-11.
// ============================================================================
constexpr int XS_S  = 264;  // shorts/row (528B = 33*16)
constexpr int H1B_S = 136;  // shorts (272B = 17*16)
constexpr int HS_S  = 68;   // floats (272B)
constexpr int NNF_S = 72;   // shorts (144B = 9*16)
constexpr int EJW   = 72;   // halfs/row ei/ej (144B = 9*16)
constexpr int SJW   = 40;   // halfs/row si/sj (80B = 5*16)

constexpr int OFF_XS  = 0;          // 33792 B
constexpr int OFF_EIH = 0;          // 9216 B  (64*72*2)
constexpr int OFF_EJH = 9216;       // 9216 B
constexpr int OFF_SIH = 18432;      // 5120 B  (64*40*2)
constexpr int OFF_SJH = 23552;      // 5120 B -> 28672 <= 33792
constexpr int OFF_H1B = 33792;      // 17408 B ; nfB alias
constexpr int OFF_HS  = 51200;      // 17408 B
constexpr int LDS_BYTES = 68608;

__global__ __launch_bounds__(1024)
void kernelF(const float* __restrict__ x,
             const float* __restrict__ b1, const float* __restrict__ b2,
             const float* __restrict__ gamma, const float* __restrict__ beta,
             const short* __restrict__ wT,
             const float* __restrict__ bE1, const float* __restrict__ E2,
             const float* __restrict__ bE2, const float* __restrict__ E3,
             const float* __restrict__ bE3, const float* __restrict__ bS1,
             const float* __restrict__ S2, const float* __restrict__ bS2,
             float* __restrict__ out_nf, float* __restrict__ out_adj,
             float* __restrict__ out_str)
{
    extern __shared__ char lds[];
    short*    XsS  = (short*)(lds + OFF_XS);
    short*    h1BS = (short*)(lds + OFF_H1B);
    float*    HsS  = (float*)(lds + OFF_HS);
    short*    nfBS = (short*)(lds + OFF_H1B);    // alias (h1B dead after ph3)
    _Float16* eihS = (_Float16*)(lds + OFF_EIH); // alias (Xs dead after ph2)
    _Float16* ejhS = (_Float16*)(lds + OFF_EJH);
    _Float16* sihS = (_Float16*)(lds + OFF_SIH);
    _Float16* sjhS = (_Float16*)(lds + OFF_SJH);
    __shared__ float bE2s[32], E3s[32];
    __shared__ _Float16 s2hS[32];

    const int t = threadIdx.x, b = blockIdx.x;
    const int w = t >> 6, l = t & 63, g = l >> 4, r = l & 15;
    const short* W1T = wT;
    const short* W2T = wT + 32768;
    const short* WcT = wT + 40960;

    if (t < 32)       bE2s[t] = bE2[t];
    else if (t < 64)  E3s[t - 32] = E3[t - 32];
    else if (t < 96)  s2hS[t - 64] = (_Float16)S2[t - 64];

    // ---- A-frags for edge MFMA: E2^T f16 (16 VGPR resident; needed every MFMA) ----
    h8 aE00, aE10, aE01, aE11;
#pragma unroll
    for (int e = 0; e < 8; ++e) {
        aE00[e] = (_Float16)E2[(size_t)(8 * g + e) * 32 + r];
        aE10[e] = (_Float16)E2[(size_t)(8 * g + e + 32) * 32 + r];
        aE01[e] = (_Float16)E2[(size_t)(8 * g + e) * 32 + r + 16];
        aE11[e] = (_Float16)E2[(size_t)(8 * g + e + 32) * 32 + r + 16];
    }
    const float bE3v = bE3[0], bS2v = bS2[0];
    const h8 z8 = {(_Float16)0.f, (_Float16)0.f, (_Float16)0.f, (_Float16)0.f,
                   (_Float16)0.f, (_Float16)0.f, (_Float16)0.f, (_Float16)0.f};

    // ---- stage X coalesced (64 rows, 16 threads/row, cvt bf16) ----
    {
        const int row = t >> 4, c0 = t & 15;
        const int srow = (row == 63) ? 127 : (int)((float)row * (127.0f / 63.0f));
        const float* xrow = x + ((size_t)b * 128 + srow) * 256;
#pragma unroll
        for (int i = 0; i < 4; ++i) {
            const int c4 = (c0 + 16 * i) * 4;
            const float4 v = *(const float4*)(xrow + c4);
            short4v s;
            s[0] = f2bf(v.x); s[1] = f2bf(v.y); s[2] = f2bf(v.z); s[3] = f2bf(v.w);
            *(short4v*)&XsS[row * XS_S + c4] = s;
        }
    }
    __syncthreads();

    // ---- ph2: h1[64][128] = relu(X@W1+b1); wave w: M-tile w>>2, N-tiles (w&3)*2+{0,1} ----
    {
        const int mt = w >> 2, nb = (w & 3) << 1;
        const int aRow = (16 * mt + r) * XS_S;
#pragma unroll
        for (int np = 0; np < 2; ++np) {
            const int n = ((nb + np) << 4) + r;
            f32x4 acca = {0.f, 0.f, 0.f, 0.f};
            f32x4 accb = {0.f, 0.f, 0.f, 0.f};
#pragma unroll
            for (int ks = 0; ks < 4; ++ks) {
                const short8 a0  = *(const short8*)&XsS[aRow + 32 * ks + 8 * g];
                const short8 a1  = *(const short8*)&XsS[aRow + 32 * (ks + 4) + 8 * g];
                const short8 bwa = *(const short8*)(W1T + (size_t)n * 256 + 32 * ks + 8 * g);
                const short8 bwb = *(const short8*)(W1T + (size_t)n * 256 + 32 * (ks + 4) + 8 * g);
                acca = __builtin_amdgcn_mfma_f32_16x16x32_bf16(a0, bwa, acca, 0, 0, 0);
                accb = __builtin_amdgcn_mfma_f32_16x16x32_bf16(a1, bwb, accb, 0, 0, 0);
            }
            const float b1v = b1[n];
#pragma unroll
            for (int q = 0; q < 4; ++q)
                h1BS[(16 * mt + 4 * g + q) * H1B_S + n] = f2bf(fmaxf(acca[q] + accb[q] + b1v, 0.f));
        }
    }
    __syncthreads();

    // ---- ph3: h[64][64] = h1@W2+b2; wave w: tile (w>>2, w&3) ----
    {
        const int mt = w >> 2;
        const int n = ((w & 3) << 4) + r;
        const int aRow = (16 * mt + r) * H1B_S;
        f32x4 acca = {0.f, 0.f, 0.f, 0.f};
        f32x4 accb = {0.f, 0.f, 0.f, 0.f};
#pragma unroll
        for (int ks2 = 0; ks2 < 2; ++ks2) {
            const short8 ha0 = *(const short8*)&h1BS[aRow + 32 * (2 * ks2) + 8 * g];
            const short8 ha1 = *(const short8*)&h1BS[aRow + 32 * (2 * ks2 + 1) + 8 * g];
            const short8 bw0 = *(const short8*)(W2T + (size_t)n * 128 + 32 * (2 * ks2) + 8 * g);
            const short8 bw1 = *(const short8*)(W2T + (size_t)n * 128 + 32 * (2 * ks2 + 1) + 8 * g);
            acca = __builtin_amdgcn_mfma_f32_16x16x32_bf16(ha0, bw0, acca, 0, 0, 0);
            accb = __builtin_amdgcn_mfma_f32_16x16x32_bf16(ha1, bw1, accb, 0, 0, 0);
        }
        const float b2v = b2[n];
#pragma unroll
        for (int q = 0; q < 4; ++q)
            HsS[(16 * mt + 4 * g + q) * HS_S + n] = acca[q] + accb[q] + b2v;
    }
    __syncthreads();

    // ---- ph4: LayerNorm; row = t>>4 (64 rows x 16 lanes exactly) ----
    {
        const int row = t >> 4, c4 = (t & 15) * 4;
        const float4 v = *(const float4*)&HsS[row * HS_S + c4];
        float s = v.x + v.y + v.z + v.w;
        s += __shfl_xor(s, 1); s += __shfl_xor(s, 2);
        s += __shfl_xor(s, 4); s += __shfl_xor(s, 8);
        const float mu = s * (1.0f / 64.0f);
        float vs = 0.f;
        { const float d0 = v.x-mu, d1 = v.y-mu, d2 = v.z-mu, d3 = v.w-mu;
          vs = fmaf(d0,d0, fmaf(d1,d1, fmaf(d2,d2, d3*d3))); }
        vs += __shfl_xor(vs, 1); vs += __shfl_xor(vs, 2);
        vs += __shfl_xor(vs, 4); vs += __shfl_xor(vs, 8);
        const float rstd = rsqrtf(vs * (1.0f / 64.0f) + 1e-5f);
        const float4 gv = *(const float4*)(gamma + c4);
        const float4 bv = *(const float4*)(beta  + c4);
        float4 o;
        o.x = fmaf((v.x - mu) * rstd, gv.x, bv.x);
        o.y = fmaf((v.y - mu) * rstd, gv.y, bv.y);
        o.z = fmaf((v.z - mu) * rstd, gv.z, bv.z);
        o.w = fmaf((v.w - mu) * rstd, gv.w, bv.w);
        *(float4*)(out_nf + (size_t)b * 4096 + (size_t)row * 64 + c4) = o;
        short4v ob;
        ob[0] = f2bf(o.x); ob[1] = f2bf(o.y); ob[2] = f2bf(o.z); ob[3] = f2bf(o.w);
        *(short4v*)&nfBS[row * NNF_S + c4] = ob;   // overwrites dead h1B region
    }
    __syncthreads();

    // ---- ph5: [ei|ej|si|sj] = nf@Wcat -> f16 LDS (Xs region), biases folded ----
    {
        const int mt = w >> 2;
        const short8 na0 = *(const short8*)&nfBS[(16 * mt + r) * NNF_S + 8 * g];
        const short8 na1 = *(const short8*)&nfBS[(16 * mt + r) * NNF_S + 32 + 8 * g];
#pragma unroll
        for (int k3 = 0; k3 < 3; ++k3) {
            const int ot = (w & 3) * 3 + k3;         // 0..11
            const int c = 16 * ot + r;
            const short8 bw0 = *(const short8*)(WcT + (size_t)c * 64 + 8 * g);
            const short8 bw1 = *(const short8*)(WcT + (size_t)c * 64 + 32 + 8 * g);
            f32x4 acc = {0.f, 0.f, 0.f, 0.f};
            acc = __builtin_amdgcn_mfma_f32_16x16x32_bf16(na0, bw0, acc, 0, 0, 0);
            acc = __builtin_amdgcn_mfma_f32_16x16x32_bf16(na1, bw1, acc, 0, 0, 0);
            if (ot < 4) {
                const float bv = bE1[c];
#pragma unroll
                for (int q = 0; q < 4; ++q)
                    eihS[(16 * mt + 4 * g + q) * EJW + c] = (_Float16)(acc[q] + bv);
            } else if (ot < 8) {
#pragma unroll
                for (int q = 0; q < 4; ++q)
                    ejhS[(16 * mt + 4 * g + q) * EJW + (c - 64)] = (_Float16)acc[q];
            } else if (ot < 10) {
                const float bv = bS1[c - 128];
#pragma unroll
                for (int q = 0; q < 4; ++q)
                    sihS[(16 * mt + 4 * g + q) * SJW + (c - 128)] = (_Float16)(acc[q] + bv);
            } else {
#pragma unroll
                for (int q = 0; q < 4; ++q)
                    sjhS[(16 * mt + 4 * g + q) * SJW + (c - 160)] = (_Float16)acc[q];
            }
        }
    }
    __syncthreads();

    // ---- E pass: wave w owns i-rows 4w..4w+3; streaming reads, inline epilogue ----
    for (int jt = 0; jt < 4; ++jt) {
        const int j = (jt << 4) + r;
        const h8 ej0 = *(const h8*)&ejhS[j * EJW + 8 * g];
        const h8 ej1 = *(const h8*)&ejhS[j * EJW + 32 + 8 * g];

#pragma unroll
        for (int ii = 0; ii < 4; ++ii) {
            const int ig = 4 * w + ii;
            const h8 ei0 = *(const h8*)&eihS[ig * EJW + 8 * g];    // broadcast b128
            const h8 ei1 = *(const h8*)&eihS[ig * EJW + 32 + 8 * g];

            const h8 b0 = __builtin_elementwise_max(ei0 + ej0, z8);
            const h8 b1 = __builtin_elementwise_max(ei1 + ej1, z8);

            f32x4 acc0 = {0.f, 0.f, 0.f, 0.f};
            f32x4 acc1 = {0.f, 0.f, 0.f, 0.f};
            acc0 = __builtin_amdgcn_mfma_f32_16x16x32_f16(aE00, b0, acc0, 0, 0, 0);
            acc0 = __builtin_amdgcn_mfma_f32_16x16x32_f16(aE10, b1, acc0, 0, 0, 0);
            acc1 = __builtin_amdgcn_mfma_f32_16x16x32_f16(aE01, b0, acc1, 0, 0, 0);
            acc1 = __builtin_amdgcn_mfma_f32_16x16x32_f16(aE11, b1, acc1, 0, 0, 0);

            float pe = 0.f;
#pragma unroll
            for (int q = 0; q < 4; ++q) {
                const int k0 = 4 * g + q;
                pe = fmaf(fmaxf(acc0[q] + bE2s[k0], 0.f), E3s[k0], pe);
                pe = fmaf(fmaxf(acc1[q] + bE2s[k0 + 16], 0.f), E3s[k0 + 16], pe);
            }
            pe += __shfl_xor(pe, 16);
            pe += __shfl_xor(pe, 32);

            if (l < 16) {
                const float z = pe + bE3v;
                const float p = 1.0f / (1.0f + __expf(-z));
                const float av = (j == ig || !(p > 0.3f)) ? 0.f : p;
                out_adj[(size_t)b * 4096 + (size_t)ig * 64 + j] = av;
            }
        }
    }

    // ---- S pass: thread t: j = t&63, i-rows (t>>6)*4..; streaming fdot2 ----
    {
        const int j = t & 63;
        const int ib = (t >> 6) * 4;
#pragma unroll
        for (int ii = 0; ii < 4; ++ii) {
            const int ig = ib + ii;
            float sacc = 0.f;
#pragma unroll
            for (int c = 0; c < 4; ++c) {
                const h8 si8 = *(const h8*)&sihS[ig * SJW + 8 * c];   // broadcast
                const h8 sj8 = *(const h8*)&sjhS[j * SJW + 8 * c];
                const h8 s2  = *(const h8*)&s2hS[8 * c];              // broadcast
                const h8 hs = __builtin_elementwise_max(si8 + sj8, z8);
                const h2 p0 = __builtin_shufflevector(hs, hs, 0, 1);
                const h2 p1 = __builtin_shufflevector(hs, hs, 2, 3);
                const h2 p2 = __builtin_shufflevector(hs, hs, 4, 5);
                const h2 p3 = __builtin_shufflevector(hs, hs, 6, 7);
                const h2 q0 = __builtin_shufflevector(s2, s2, 0, 1);
                const h2 q1 = __builtin_shufflevector(s2, s2, 2, 3);
                const h2 q2 = __builtin_shufflevector(s2, s2, 4, 5);
                const h2 q3 = __builtin_shufflevector(s2, s2, 6, 7);
                sacc = __builtin_amdgcn_fdot2(p0, q0, sacc, false);
                sacc = __builtin_amdgcn_fdot2(p1, q1, sacc, false);
                sacc = __builtin_amdgcn_fdot2(p2, q2, sacc, false);
                sacc = __builtin_amdgcn_fdot2(p3, q3, sacc, false);
            }
            const float xs = sacc + bS2v;
            const float e2x = __expf(2.0f * xs);
            const float sv = (j == ig) ? 0.f : (e2x - 1.0f) / (e2x + 1.0f);
            out_str[(size_t)b * 4096 + (size_t)ig * 64 + j] = sv;
        }
    }
}

extern "C" void kernel_launch(void* const* d_in, const int* in_sizes, int n_in,
                              void* d_out, int out_size, void* d_ws, size_t ws_size,
                              hipStream_t stream)
{
    const float* x     = (const float*)d_in[0];
    const float* W1    = (const float*)d_in[1];
    const float* b1    = (const float*)d_in[2];
    const float* W2    = (const float*)d_in[3];
    const float* b2    = (const float*)d_in[4];
    const float* gamma = (const float*)d_in[5];
    const float* beta  = (const float*)d_in[6];
    const float* E1    = (const float*)d_in[7];
    const float* bE1   = (const float*)d_in[8];
    const float* E2    = (const float*)d_in[9];
    const float* bE2   = (const float*)d_in[10];
    const float* E3    = (const float*)d_in[11];
    const float* bE3   = (const float*)d_in[12];
    const float* S1    = (const float*)d_in[13];
    const float* bS1   = (const float*)d_in[14];
    const float* S2    = (const float*)d_in[15];
    const float* bS2   = (const float*)d_in[16];

    float* out     = (float*)d_out;
    float* out_nf  = out;                // 256*64*64
    float* out_adj = out + 1048576;
    float* out_str = out + 2097152;

    short* wT = (short*)d_ws;            // 104 KB scratch, rewritten every call

    (void)hipFuncSetAttribute((const void*)kernelF,
        hipFuncAttributeMaxDynamicSharedMemorySize, LDS_BYTES);

    kernelA0<<<128, 256, 0, stream>>>(W1, W2, E1, S1, wT);

    kernelF<<<256, 1024, LDS_BYTES, stream>>>(
        x, b1, b2, gamma, beta, wT,
        bE1, E2, bE2, E3, bE3, bS1, S2, bS2,
        out_nf, out_adj, out_str);
}